// Round 12
// baseline (208.264 us; speedup 1.0000x reference)
//
#include <hip/hip_runtime.h>
#include <cmath>

typedef short short8 __attribute__((ext_vector_type(8)));
typedef short short4v __attribute__((ext_vector_type(4)));
typedef float f32x16 __attribute__((ext_vector_type(16)));

#define EPSF 1.1920929e-07f

// ---------------- LDS layout (bytes), total 141312 (M=64, 1 block/CU) --------
#define LDS_A2W 0        // [64][264] ushort bf16
#define LDS_A2H 33792    // [64][264] ushort
#define LDS_A1W 67584    // [64][264] ushort (dead after L2)
#define LDS_A1H 101376   // [64][264] ushort (dead after L2)
#define LDS_XA  135168   // [64][16]  ushort (dead after L1)
#define LDS_EW  67584    // [64][288] ushort e = exp(raw_w)   (overlays A1W)
#define LDS_HH  104448   // [64][288] ushort h = softplus+EPS (overlays A1H+XA)
#define LDS_TOTAL 141312

// ---------------- packed weights (ushort elements) in d_ws ----------------
// B-frag for mfma_f32_32x32x16_bf16: lane l holds B[k=(l>>5)*8+e][n=l&31]
// tile = 512 ushort; storage order [nt][kt] (kt contiguous -> imm-offset folding)
#define OFF1H 0        // 8 tiles   (K=16: 1 kt x 8 nt)
#define OFF1W 4096
#define OFF2H 8192     // 128 tiles (8 nt x 16 kt)
#define OFF2W 73728
#define OFF3H 139264   // 272 tiles (17 nt x 16 kt, cols>=528 zero)
#define OFF3W 278528   // 256 tiles (16 nt x 16 kt)

// lgkm-only barrier: LDS producer->consumer is fenced, but vmcnt (global weight
// prefetches) survives the barrier -- the T3/T4 counted-vmcnt idiom in plain HIP.
#define LGKM_BARRIER() do { \
  asm volatile("s_waitcnt lgkmcnt(0)" ::: "memory"); \
  __builtin_amdgcn_s_barrier(); \
} while (0)

__device__ __forceinline__ unsigned short f2bf(float f) {   // round-half-up
  union { float f; unsigned u; } v; v.f = f;
  return (unsigned short)((v.u + 0x8000u) >> 16);
}
__device__ __forceinline__ float bf2f(unsigned short h) {
  union { unsigned u; float f; } v; v.u = ((unsigned)h) << 16; return v.f;
}

__global__ void pack_weights(const float* __restrict__ hW1, const float* __restrict__ wW1,
                             const float* __restrict__ hW2, const float* __restrict__ wW2,
                             const float* __restrict__ hW3, const float* __restrict__ wW3,
                             unsigned short* __restrict__ out) {
  int tile = blockIdx.x, l = threadIdx.x;
  const float* src; unsigned short* dst; int NT, N, K, base;
  if (tile < 8)        { src = hW1; dst = out + OFF1H; NT = 8;  N = 256; K = 16;  base = tile; }
  else if (tile < 16)  { src = wW1; dst = out + OFF1W; NT = 8;  N = 256; K = 16;  base = tile - 8; }
  else if (tile < 144) { src = hW2; dst = out + OFF2H; NT = 8;  N = 256; K = 256; base = tile - 16; }
  else if (tile < 272) { src = wW2; dst = out + OFF2W; NT = 8;  N = 256; K = 256; base = tile - 144; }
  else if (tile < 544) { src = hW3; dst = out + OFF3H; NT = 17; N = 528; K = 256; base = tile - 272; }
  else                 { src = wW3; dst = out + OFF3W; NT = 16; N = 512; K = 256; base = tile - 544; }
  int nt = base % NT, kt = base / NT, KTT = K / 16;
  int n = nt * 32 + (l & 31);
  int k0 = kt * 16 + (l >> 5) * 8;
  short8 v;
  #pragma unroll
  for (int e = 0; e < 8; e++) {
    float f = (n < N && (k0 + e) < K) ? src[(k0 + e) * N + n] : 0.f;
    v[e] = (short)f2bf(f);
  }
  int idx = nt * KTT + kt;
  *(short8*)(dst + (idx * 64 + l) * 8) = v;
}

struct Acc2 { f32x16 a0, a1; };

#define MFMA(A, B, C) __builtin_amdgcn_mfma_f32_32x32x16_bf16((A), (B), (C), 0, 0, 0)

__device__ __forceinline__ Acc2 acc_init(float v) {
  Acc2 r;
  #pragma unroll
  for (int i = 0; i < 16; i++) { r.a0[i] = v; r.a1[i] = v; }
  return r;
}

// C layout (m74/m101): col = lane&31, row = (reg&3) + 8*(reg>>2) + 4*(lane>>5)
__device__ __forceinline__ void epi_relu2(char* lds, int oOff, const Acc2& a, int ct) {
  int l = threadIdx.x & 63;
  int col = ct * 32 + (l & 31);
  unsigned short* o = (unsigned short*)(lds + oOff) + col + 4 * (l >> 5) * 264;
  #pragma unroll
  for (int r = 0; r < 16; r++) {
    int row = (r & 3) + 8 * (r >> 2);
    o[row * 264] = f2bf(fmaxf(a.a0[r], 0.f));
    o[(row + 32) * 264] = f2bf(fmaxf(a.a1[r], 0.f));
  }
}

// G3 epilogue (R11-identical): wnet -> e=exp to EW; else softplus to HH (cols owned by half H)
__device__ __forceinline__ void g3_epi(char* lds, const Acc2& a, int ctg, int H, bool wnet) {
  int l = threadIdx.x & 63;
  if (wnet) {
    unsigned short* o = (unsigned short*)(lds + LDS_EW) + (ctg & 7) * 36 + (l & 31)
                        + 4 * (l >> 5) * 288;
    #pragma unroll
    for (int r = 0; r < 16; r++) {
      int row = (r & 3) + 8 * (r >> 2);
      o[row * 288] = f2bf(__expf(a.a0[r]));
      o[(row + 32) * 288] = f2bf(__expf(a.a1[r]));
    }
  } else {
    int c = ctg * 32 + (l & 31);
    if (c >= 264 * H && c < 264 * (H + 1)) {
      unsigned d = ((unsigned)c * 993u) >> 15;  // c/33 for c<544
      int j = c - 33 * (int)d;
      unsigned short* o = (unsigned short*)(lds + LDS_HH) + ((int)d & 7) * 36 + j
                          + 4 * (l >> 5) * 288;
      #pragma unroll
      for (int r = 0; r < 16; r++) {
        int row = (r & 3) + 8 * (r >> 2);
        float v0 = a.a0[r];
        o[row * 288] = f2bf(fmaxf(v0, 0.f) + __logf(1.f + __expf(-fabsf(v0))) + EPSF);
        float v1 = a.a1[r];
        o[(row + 32) * 288] = f2bf(fmaxf(v1, 0.f) + __logf(1.f + __expf(-fabsf(v1))) + EPSF);
      }
    }
  }
}

// spline (R11-identical except xbv passed in, preloaded at kernel top)
__device__ __forceinline__ void spline_phase(char* lds, int t, int H, float xbv,
                                             float* __restrict__ y, int r0) {
  int p = t >> 1, half = t & 1;
  int row = p >> 3, dl = p & 7, dg = H * 8 + dl;
  const unsigned short* EWb = (const unsigned short*)(lds + LDS_EW) + row * 288 + dl * 36;
  const unsigned short* HHb = (const unsigned short*)(lds + LDS_HH) + row * 288 + dl * 36;
  const unsigned short* EWp = EWb + half * 16;
  const unsigned short* HHp = HHb + half * 16;
  float e[16], hh[17];
  #pragma unroll
  for (int i = 0; i < 4; i++) {
    short4v ev = *(const short4v*)(EWp + i * 4);
    short4v hv = *(const short4v*)(HHp + i * 4);
    #pragma unroll
    for (int jj = 0; jj < 4; jj++) {
      e[i * 4 + jj] = bf2f((unsigned short)ev[jj]);
      hh[i * 4 + jj] = bf2f((unsigned short)hv[jj]);
    }
  }
  hh[16] = bf2f(HHp[16]);
  float se = 0.f;
  #pragma unroll
  for (int k = 0; k < 16; k++) se += e[k];
  float so = __shfl_xor(se, 1);
  float s = se + so;
  float xbs = xbv * s;
  float bl0 = half ? so : 0.f;
  int fnd = (xbs >= bl0) ? 1 : 0;
  float bl = bl0, cl2 = 0.f, sxl = bl0, scl2 = 0.f;
  int ki = 0;
  #pragma unroll
  for (int k = 0; k < 16; k++) {
    bool c = (xbs >= bl);
    ki   = c ? k   : ki;
    sxl  = c ? bl  : sxl;
    scl2 = c ? cl2 : scl2;
    cl2 += (hh[k] + hh[k + 1]) * e[k];
    bl  += e[k];
  }
  float cl2o = __shfl_xor(cl2, 1);
  float S2 = cl2 + cl2o;
  if (half) scl2 += cl2o;            // globalize half1's area prefix
  int   o_ki   = __shfl_xor(ki, 1);
  float o_sxl  = __shfl_xor(sxl, 1);
  float o_scl2 = __shfl_xor(scl2, 1);
  int   o_fnd  = __shfl_xor(fnd, 1);
  bool other = half ? (fnd == 0) : (o_fnd != 0);
  int   gki   = other ? o_ki   : ki;
  int   ghalf = other ? (half ^ 1) : half;
  float gsxl  = other ? o_sxl  : sxl;
  float gscl2 = other ? o_scl2 : scl2;
  int go = ghalf * 16 + gki;
  float sew = bf2f(EWb[go]);
  float shl = bf2f(HHb[go]);
  float shr = bf2f(HHb[go + 1]);
  float alpha = (xbs - gsxl) / (sew + EPSF);
  float yv = (gscl2 + (alpha * alpha * (shr - shl) + 2.f * alpha * shl) * sew) / S2;
  if (!half) y[(r0 + row) * 32 + 2 * dg + 1] = yv;
}

// __launch_bounds__ 2nd arg = min BLOCKS/CU on this toolchain (R8/R10 evidence).
// (1024,1): 16 waves = 4 waves/SIMD -> VGPR cap 128 (prefetch arrays need it).
__global__ __launch_bounds__(1024, 1) void fused_kernel(
    const float* __restrict__ x,
    const float* __restrict__ hb1, const float* __restrict__ hb2, const float* __restrict__ hb3,
    const float* __restrict__ wb1, const float* __restrict__ wb2, const float* __restrict__ wb3,
    const unsigned short* __restrict__ pw,
    float* __restrict__ y) {
  extern __shared__ char lds[];
  const int t = threadIdx.x;
  const int w = t >> 6, l = t & 63;
  const int r0 = blockIdx.x * 64;
  const bool wnet = (w < 8);
  const int ct8 = w & 7;

  // ---- early global issues: x tile, spline x values (oldest in vm queue) ----
  float4 xv;
  int xrow = t >> 3, xc4 = t & 7;
  if (t < 512) xv = *(const float4*)(x + (r0 + xrow) * 32 + xc4 * 4);
  int sp_p = t >> 1;
  int sp_row = sp_p >> 3, sp_dl = sp_p & 7;
  float xs0 = x[(r0 + sp_row) * 32 + 2 * sp_dl + 1];
  float xs1 = x[(r0 + sp_row) * 32 + 2 * (8 + sp_dl) + 1];

  // ---- weight prefetch: L1 frag + all 16 L2 frags ----
  const unsigned short* bL1 = pw + (wnet ? OFF1W : OFF1H) + (ct8 * 64 + l) * 8;
  const unsigned short* bL2 = pw + (wnet ? OFF2W : OFF2H) + (ct8 * 16 * 64 + l) * 8;
  short8 fL1 = *(const short8*)bL1;
  short8 fL2[16];
  #pragma unroll
  for (int kt = 0; kt < 16; kt++) fL2[kt] = *(const short8*)(bL2 + kt * 512);

  // ---- P0: stage xA bf16 [64][16], emit y even cols ----
  if (t < 512) {
    y[(r0 + xrow) * 32 + xc4 * 4] = xv.x;
    y[(r0 + xrow) * 32 + xc4 * 4 + 2] = xv.z;
    unsigned short* xa = (unsigned short*)(lds + LDS_XA) + xrow * 16 + xc4 * 2;
    xa[0] = f2bf(xv.x); xa[1] = f2bf(xv.z);
  }
  LGKM_BARRIER();

  const unsigned short* XA  = (const unsigned short*)(lds + LDS_XA);
  const int col8 = ct8 * 32 + (l & 31);

  // ---- L1 (K=16): consume fL1 ----
  {
    Acc2 r = acc_init(wnet ? wb1[col8] : hb1[col8]);
    const unsigned short* a0p = XA + (l & 31) * 16 + (l >> 5) * 8;
    short8 a0 = *(const short8*)a0p;
    short8 a1 = *(const short8*)(a0p + 32 * 16);
    r.a0 = MFMA(a0, fL1, r.a0);
    r.a1 = MFMA(a1, fL1, r.a1);
    epi_relu2(lds, wnet ? LDS_A1W : LDS_A1H, r, ct8);
  }
  LGKM_BARRIER();

  // ---- L2: consume fL2, issue fG3a (this wave's G3 half-0 fragments) ----
  const int ctg0 = wnet ? w : (w - 8);
  const int ctg1 = ctg0 + 8;
  const unsigned short* bG3a = pw + (wnet ? OFF3W : OFF3H) + (ctg0 * 16 * 64 + l) * 8;
  const unsigned short* bG3b = pw + (wnet ? OFF3W : OFF3H) + (ctg1 * 16 * 64 + l) * 8;
  short8 fG3a[16];
  {
    Acc2 r = acc_init(wnet ? wb2[col8] : hb2[col8]);
    const unsigned short* A1n = (const unsigned short*)(lds + (wnet ? LDS_A1W : LDS_A1H));
    const unsigned short* a0p = A1n + (l & 31) * 264 + (l >> 5) * 8;
    #pragma unroll
    for (int kt = 0; kt < 16; kt++) {
      short8 a0 = *(const short8*)(a0p + kt * 16);
      short8 a1 = *(const short8*)(a0p + 32 * 264 + kt * 16);
      r.a0 = MFMA(a0, fL2[kt], r.a0);
      r.a1 = MFMA(a1, fL2[kt], r.a1);
      fG3a[kt] = *(const short8*)(bG3a + kt * 512);
    }
    epi_relu2(lds, wnet ? LDS_A2W : LDS_A2H, r, ct8);
  }
  LGKM_BARRIER();

  const unsigned short* A2n = (const unsigned short*)(lds + (wnet ? LDS_A2W : LDS_A2H));
  const unsigned short* a2p = A2n + (l & 31) * 264 + (l >> 5) * 8;
  const unsigned short* A2Hp = (const unsigned short*)(lds + LDS_A2H);
  const unsigned short* a2hp = A2Hp + (l & 31) * 264 + (l >> 5) * 8;

  // ---- G3 half 0: consume fG3a, issue fG3b ----
  short8 fG3b[16];
  {
    float binit;
    if (wnet) binit = wb3[ctg0 * 32 + (l & 31)];
    else { int c = ctg0 * 32 + (l & 31); binit = (c < 528) ? hb3[c] : 0.f; }
    Acc2 a = acc_init(binit);
    #pragma unroll
    for (int kt = 0; kt < 16; kt++) {
      short8 a0 = *(const short8*)(a2p + kt * 16);
      short8 a1 = *(const short8*)(a2p + 32 * 264 + kt * 16);
      a.a0 = MFMA(a0, fG3a[kt], a.a0);
      a.a1 = MFMA(a1, fG3a[kt], a.a1);
      fG3b[kt] = *(const short8*)(bG3b + kt * 512);
    }
    g3_epi(lds, a, ctg0, 0, wnet);
  }
  if (w == 0) {   // straggler unit: h-net tile 8 (cold loads, as in R11)
    const unsigned short* bx = pw + OFF3H + (8 * 16 * 64 + l) * 8;
    int c = 8 * 32 + (l & 31);
    Acc2 a = acc_init((c < 528) ? hb3[c] : 0.f);
    #pragma unroll
    for (int kt = 0; kt < 16; kt++) {
      short8 a0 = *(const short8*)(a2hp + kt * 16);
      short8 a1 = *(const short8*)(a2hp + 32 * 264 + kt * 16);
      short8 b = *(const short8*)(bx + kt * 512);
      a.a0 = MFMA(a0, b, a.a0);
      a.a1 = MFMA(a1, b, a.a1);
    }
    g3_epi(lds, a, 8, 0, false);
  }
  LGKM_BARRIER();

  spline_phase(lds, t, 0, xs0, y, r0);
  LGKM_BARRIER();

  // ---- G3 half 1: consume fG3b ----
  {
    float binit;
    if (wnet) binit = wb3[ctg1 * 32 + (l & 31)];
    else { int c = ctg1 * 32 + (l & 31); binit = (c < 528) ? hb3[c] : 0.f; }
    Acc2 a = acc_init(binit);
    #pragma unroll
    for (int kt = 0; kt < 16; kt++) {
      short8 a0 = *(const short8*)(a2p + kt * 16);
      short8 a1 = *(const short8*)(a2p + 32 * 264 + kt * 16);
      a.a0 = MFMA(a0, fG3b[kt], a.a0);
      a.a1 = MFMA(a1, fG3b[kt], a.a1);
    }
    g3_epi(lds, a, ctg1, 1, wnet);
  }
  if (w == 0) {   // straggler unit: h-net tile 16 (cold loads)
    const unsigned short* bx = pw + OFF3H + (16 * 16 * 64 + l) * 8;
    int c = 16 * 32 + (l & 31);
    Acc2 a = acc_init((c < 528) ? hb3[c] : 0.f);
    #pragma unroll
    for (int kt = 0; kt < 16; kt++) {
      short8 a0 = *(const short8*)(a2hp + kt * 16);
      short8 a1 = *(const short8*)(a2hp + 32 * 264 + kt * 16);
      short8 b = *(const short8*)(bx + kt * 512);
      a.a0 = MFMA(a0, b, a.a0);
      a.a1 = MFMA(a1, b, a.a1);
    }
    g3_epi(lds, a, 16, 1, false);
  }
  LGKM_BARRIER();

  spline_phase(lds, t, 1, xs1, y, r0);
}

extern "C" void kernel_launch(void* const* d_in, const int* in_sizes, int n_in,
                              void* d_out, int out_size, void* d_ws, size_t ws_size,
                              hipStream_t stream) {
  const float* x   = (const float*)d_in[0];
  const float* hW1 = (const float*)d_in[1];
  const float* hb1 = (const float*)d_in[2];
  const float* hW2 = (const float*)d_in[3];
  const float* hb2 = (const float*)d_in[4];
  const float* hW3 = (const float*)d_in[5];
  const float* hb3 = (const float*)d_in[6];
  const float* wW1 = (const float*)d_in[7];
  const float* wb1 = (const float*)d_in[8];
  const float* wW2 = (const float*)d_in[9];
  const float* wb2 = (const float*)d_in[10];
  const float* wW3 = (const float*)d_in[11];
  const float* wb3 = (const float*)d_in[12];
  unsigned short* pw = (unsigned short*)d_ws;

  pack_weights<<<800, 64, 0, stream>>>(hW1, wW1, hW2, wW2, hW3, wW3, pw);

  hipFuncSetAttribute((const void*)fused_kernel,
                      hipFuncAttributeMaxDynamicSharedMemorySize, LDS_TOTAL);
  fused_kernel<<<2048, 1024, LDS_TOTAL, stream>>>(
      x, hb1, hb2, hb3, wb1, wb2, wb3, pw, (float*)d_out);
}

// Round 13
// 202.467 us; speedup vs baseline: 1.0286x; 1.0286x over previous
//
#include <hip/hip_runtime.h>
#include <cmath>

typedef short short8 __attribute__((ext_vector_type(8)));
typedef short short4v __attribute__((ext_vector_type(4)));
typedef float f32x16 __attribute__((ext_vector_type(16)));

#define EPSF 1.1920929e-07f

// ---------------- LDS layout (bytes), total 141312 (M=64, 1 block/CU) --------
#define LDS_A2W 0        // [64][264] ushort bf16
#define LDS_A2H 33792    // [64][264] ushort
#define LDS_A1W 67584    // [64][264] ushort (dead after L2)
#define LDS_A1H 101376   // [64][264] ushort (dead after L2)
#define LDS_XA  135168   // [64][16]  ushort (dead after L1)
#define LDS_EW  67584    // [64][288] ushort e = exp(raw_w)   (overlays A1W)
#define LDS_HH  104448   // [64][288] ushort h = softplus+EPS (overlays A1H+XA)
#define LDS_TOTAL 141312

// ---------------- packed weights (ushort elements) in d_ws ----------------
// B-frag for mfma_f32_32x32x16_bf16: lane l holds B[k=(l>>5)*8+e][n=l&31]
// tile = 512 ushort; storage order [nt][kt] (kt contiguous -> imm-offset folding)
#define OFF1H 0        // 8 tiles   (K=16: 1 kt x 8 nt)
#define OFF1W 4096
#define OFF2H 8192     // 128 tiles (8 nt x 16 kt)
#define OFF2W 73728
#define OFF3H 139264   // 272 tiles (17 nt x 16 kt, cols>=528 zero)
#define OFF3W 278528   // 256 tiles (16 nt x 16 kt)

// lgkm-only barrier: LDS producer->consumer is fenced, but vmcnt (global weight
// prefetches) survives the barrier -- the T3/T4 counted-vmcnt idiom in plain HIP.
#define LGKM_BARRIER() do { \
  asm volatile("s_waitcnt lgkmcnt(0)" ::: "memory"); \
  __builtin_amdgcn_s_barrier(); \
} while (0)

__device__ __forceinline__ unsigned short f2bf(float f) {   // round-half-up
  union { float f; unsigned u; } v; v.f = f;
  return (unsigned short)((v.u + 0x8000u) >> 16);
}
__device__ __forceinline__ float bf2f(unsigned short h) {
  union { unsigned u; float f; } v; v.u = ((unsigned)h) << 16; return v.f;
}

__global__ void pack_weights(const float* __restrict__ hW1, const float* __restrict__ wW1,
                             const float* __restrict__ hW2, const float* __restrict__ wW2,
                             const float* __restrict__ hW3, const float* __restrict__ wW3,
                             unsigned short* __restrict__ out) {
  int tile = blockIdx.x, l = threadIdx.x;
  const float* src; unsigned short* dst; int NT, N, K, base;
  if (tile < 8)        { src = hW1; dst = out + OFF1H; NT = 8;  N = 256; K = 16;  base = tile; }
  else if (tile < 16)  { src = wW1; dst = out + OFF1W; NT = 8;  N = 256; K = 16;  base = tile - 8; }
  else if (tile < 144) { src = hW2; dst = out + OFF2H; NT = 8;  N = 256; K = 256; base = tile - 16; }
  else if (tile < 272) { src = wW2; dst = out + OFF2W; NT = 8;  N = 256; K = 256; base = tile - 144; }
  else if (tile < 544) { src = hW3; dst = out + OFF3H; NT = 17; N = 528; K = 256; base = tile - 272; }
  else                 { src = wW3; dst = out + OFF3W; NT = 16; N = 512; K = 256; base = tile - 544; }
  int nt = base % NT, kt = base / NT, KTT = K / 16;
  int n = nt * 32 + (l & 31);
  int k0 = kt * 16 + (l >> 5) * 8;
  short8 v;
  #pragma unroll
  for (int e = 0; e < 8; e++) {
    float f = (n < N && (k0 + e) < K) ? src[(k0 + e) * N + n] : 0.f;
    v[e] = (short)f2bf(f);
  }
  int idx = nt * KTT + kt;
  *(short8*)(dst + (idx * 64 + l) * 8) = v;
}

struct Acc2 { f32x16 a0, a1; };

#define MFMA(A, B, C) __builtin_amdgcn_mfma_f32_32x32x16_bf16((A), (B), (C), 0, 0, 0)

__device__ __forceinline__ Acc2 acc_init(float v) {
  Acc2 r;
  #pragma unroll
  for (int i = 0; i < 16; i++) { r.a0[i] = v; r.a1[i] = v; }
  return r;
}

// C layout (m74/m101): col = lane&31, row = (reg&3) + 8*(reg>>2) + 4*(lane>>5)
__device__ __forceinline__ void epi_relu2(char* lds, int oOff, const Acc2& a, int ct) {
  int l = threadIdx.x & 63;
  int col = ct * 32 + (l & 31);
  unsigned short* o = (unsigned short*)(lds + oOff) + col + 4 * (l >> 5) * 264;
  #pragma unroll
  for (int r = 0; r < 16; r++) {
    int row = (r & 3) + 8 * (r >> 2);
    o[row * 264] = f2bf(fmaxf(a.a0[r], 0.f));
    o[(row + 32) * 264] = f2bf(fmaxf(a.a1[r], 0.f));
  }
}

// G3 epilogue: wnet -> e=exp to EW; else softplus to HH (cols owned by half H)
__device__ __forceinline__ void g3_epi(char* lds, const Acc2& a, int ctg, int H, bool wnet) {
  int l = threadIdx.x & 63;
  if (wnet) {
    unsigned short* o = (unsigned short*)(lds + LDS_EW) + (ctg & 7) * 36 + (l & 31)
                        + 4 * (l >> 5) * 288;
    #pragma unroll
    for (int r = 0; r < 16; r++) {
      int row = (r & 3) + 8 * (r >> 2);
      o[row * 288] = f2bf(__expf(a.a0[r]));
      o[(row + 32) * 288] = f2bf(__expf(a.a1[r]));
    }
  } else {
    int c = ctg * 32 + (l & 31);
    if (c >= 264 * H && c < 264 * (H + 1)) {
      unsigned d = ((unsigned)c * 993u) >> 15;  // c/33 for c<544
      int j = c - 33 * (int)d;
      unsigned short* o = (unsigned short*)(lds + LDS_HH) + ((int)d & 7) * 36 + j
                          + 4 * (l >> 5) * 288;
      #pragma unroll
      for (int r = 0; r < 16; r++) {
        int row = (r & 3) + 8 * (r >> 2);
        float v0 = a.a0[r];
        o[row * 288] = f2bf(fmaxf(v0, 0.f) + __logf(1.f + __expf(-fabsf(v0))) + EPSF);
        float v1 = a.a1[r];
        o[(row + 32) * 288] = f2bf(fmaxf(v1, 0.f) + __logf(1.f + __expf(-fabsf(v1))) + EPSF);
      }
    }
  }
}

// spline (R11-identical except xbv passed in, preloaded at kernel top)
__device__ __forceinline__ void spline_phase(char* lds, int t, int H, float xbv,
                                             float* __restrict__ y, int r0) {
  int p = t >> 1, half = t & 1;
  int row = p >> 3, dl = p & 7, dg = H * 8 + dl;
  const unsigned short* EWb = (const unsigned short*)(lds + LDS_EW) + row * 288 + dl * 36;
  const unsigned short* HHb = (const unsigned short*)(lds + LDS_HH) + row * 288 + dl * 36;
  const unsigned short* EWp = EWb + half * 16;
  const unsigned short* HHp = HHb + half * 16;
  float e[16], hh[17];
  #pragma unroll
  for (int i = 0; i < 4; i++) {
    short4v ev = *(const short4v*)(EWp + i * 4);
    short4v hv = *(const short4v*)(HHp + i * 4);
    #pragma unroll
    for (int jj = 0; jj < 4; jj++) {
      e[i * 4 + jj] = bf2f((unsigned short)ev[jj]);
      hh[i * 4 + jj] = bf2f((unsigned short)hv[jj]);
    }
  }
  hh[16] = bf2f(HHp[16]);
  float se = 0.f;
  #pragma unroll
  for (int k = 0; k < 16; k++) se += e[k];
  float so = __shfl_xor(se, 1);
  float s = se + so;
  float xbs = xbv * s;
  float bl0 = half ? so : 0.f;
  int fnd = (xbs >= bl0) ? 1 : 0;
  float bl = bl0, cl2 = 0.f, sxl = bl0, scl2 = 0.f;
  int ki = 0;
  #pragma unroll
  for (int k = 0; k < 16; k++) {
    bool c = (xbs >= bl);
    ki   = c ? k   : ki;
    sxl  = c ? bl  : sxl;
    scl2 = c ? cl2 : scl2;
    cl2 += (hh[k] + hh[k + 1]) * e[k];
    bl  += e[k];
  }
  float cl2o = __shfl_xor(cl2, 1);
  float S2 = cl2 + cl2o;
  if (half) scl2 += cl2o;            // globalize half1's area prefix
  int   o_ki   = __shfl_xor(ki, 1);
  float o_sxl  = __shfl_xor(sxl, 1);
  float o_scl2 = __shfl_xor(scl2, 1);
  int   o_fnd  = __shfl_xor(fnd, 1);
  bool other = half ? (fnd == 0) : (o_fnd != 0);
  int   gki   = other ? o_ki   : ki;
  int   ghalf = other ? (half ^ 1) : half;
  float gsxl  = other ? o_sxl  : sxl;
  float gscl2 = other ? o_scl2 : scl2;
  int go = ghalf * 16 + gki;
  float sew = bf2f(EWb[go]);
  float shl = bf2f(HHb[go]);
  float shr = bf2f(HHb[go + 1]);
  float alpha = (xbs - gsxl) / (sew + EPSF);
  float yv = (gscl2 + (alpha * alpha * (shr - shl) + 2.f * alpha * shl) * sew) / S2;
  if (!half) y[(r0 + row) * 32 + 2 * dg + 1] = yv;
}

// __launch_bounds__ minBlocks=1 alone lets the allocator self-cap at 64 VGPR
// (8 waves/EU heuristic -> R11 chose 40, R12 chose 64 + spilled the prefetch
// arrays). amdgpu_waves_per_eu(4,4) pins the target at 4 waves/EU (which the
// 141 KB LDS already enforces) -> full 128-VGPR budget for the prefetch arrays.
__global__ __launch_bounds__(1024, 1) __attribute__((amdgpu_waves_per_eu(4, 4)))
void fused_kernel(
    const float* __restrict__ x,
    const float* __restrict__ hb1, const float* __restrict__ hb2, const float* __restrict__ hb3,
    const float* __restrict__ wb1, const float* __restrict__ wb2, const float* __restrict__ wb3,
    const unsigned short* __restrict__ pw,
    float* __restrict__ y) {
  extern __shared__ char lds[];
  const int t = threadIdx.x;
  const int w = t >> 6, l = t & 63;
  const int r0 = blockIdx.x * 64;
  const bool wnet = (w < 8);
  const int ct8 = w & 7;

  // ---- early global issues: x tile, spline x values (oldest in vm queue) ----
  float4 xv;
  int xrow = t >> 3, xc4 = t & 7;
  if (t < 512) xv = *(const float4*)(x + (r0 + xrow) * 32 + xc4 * 4);
  int sp_p = t >> 1;
  int sp_row = sp_p >> 3, sp_dl = sp_p & 7;
  float xs0 = x[(r0 + sp_row) * 32 + 2 * sp_dl + 1];
  float xs1 = x[(r0 + sp_row) * 32 + 2 * (8 + sp_dl) + 1];

  // ---- weight prefetch: L1 frag + all 16 L2 frags ----
  const unsigned short* bL1 = pw + (wnet ? OFF1W : OFF1H) + (ct8 * 64 + l) * 8;
  const unsigned short* bL2 = pw + (wnet ? OFF2W : OFF2H) + (ct8 * 16 * 64 + l) * 8;
  short8 fL1 = *(const short8*)bL1;
  short8 fL2[16];
  #pragma unroll
  for (int kt = 0; kt < 16; kt++) fL2[kt] = *(const short8*)(bL2 + kt * 512);

  // ---- P0: stage xA bf16 [64][16], emit y even cols ----
  if (t < 512) {
    y[(r0 + xrow) * 32 + xc4 * 4] = xv.x;
    y[(r0 + xrow) * 32 + xc4 * 4 + 2] = xv.z;
    unsigned short* xa = (unsigned short*)(lds + LDS_XA) + xrow * 16 + xc4 * 2;
    xa[0] = f2bf(xv.x); xa[1] = f2bf(xv.z);
  }
  LGKM_BARRIER();

  const unsigned short* XA  = (const unsigned short*)(lds + LDS_XA);
  const int col8 = ct8 * 32 + (l & 31);

  // ---- L1 (K=16): consume fL1 ----
  {
    Acc2 r = acc_init(wnet ? wb1[col8] : hb1[col8]);
    const unsigned short* a0p = XA + (l & 31) * 16 + (l >> 5) * 8;
    short8 a0 = *(const short8*)a0p;
    short8 a1 = *(const short8*)(a0p + 32 * 16);
    r.a0 = MFMA(a0, fL1, r.a0);
    r.a1 = MFMA(a1, fL1, r.a1);
    epi_relu2(lds, wnet ? LDS_A1W : LDS_A1H, r, ct8);
  }
  LGKM_BARRIER();

  // ---- L2: consume fL2, issue fG3a (this wave's G3 half-0 fragments) ----
  const int ctg0 = wnet ? w : (w - 8);
  const int ctg1 = ctg0 + 8;
  const unsigned short* bG3a = pw + (wnet ? OFF3W : OFF3H) + (ctg0 * 16 * 64 + l) * 8;
  const unsigned short* bG3b = pw + (wnet ? OFF3W : OFF3H) + (ctg1 * 16 * 64 + l) * 8;
  short8 fG3a[16];
  {
    Acc2 r = acc_init(wnet ? wb2[col8] : hb2[col8]);
    const unsigned short* A1n = (const unsigned short*)(lds + (wnet ? LDS_A1W : LDS_A1H));
    const unsigned short* a0p = A1n + (l & 31) * 264 + (l >> 5) * 8;
    #pragma unroll
    for (int kt = 0; kt < 16; kt++) {
      short8 a0 = *(const short8*)(a0p + kt * 16);
      short8 a1 = *(const short8*)(a0p + 32 * 264 + kt * 16);
      r.a0 = MFMA(a0, fL2[kt], r.a0);
      r.a1 = MFMA(a1, fL2[kt], r.a1);
      fG3a[kt] = *(const short8*)(bG3a + kt * 512);
    }
    epi_relu2(lds, wnet ? LDS_A2W : LDS_A2H, r, ct8);
  }
  LGKM_BARRIER();

  const unsigned short* A2n = (const unsigned short*)(lds + (wnet ? LDS_A2W : LDS_A2H));
  const unsigned short* a2p = A2n + (l & 31) * 264 + (l >> 5) * 8;
  const unsigned short* A2Hp = (const unsigned short*)(lds + LDS_A2H);
  const unsigned short* a2hp = A2Hp + (l & 31) * 264 + (l >> 5) * 8;

  // ---- G3 half 0: consume fG3a ----
  {
    float binit;
    if (wnet) binit = wb3[ctg0 * 32 + (l & 31)];
    else { int c = ctg0 * 32 + (l & 31); binit = (c < 528) ? hb3[c] : 0.f; }
    Acc2 a = acc_init(binit);
    #pragma unroll
    for (int kt = 0; kt < 16; kt++) {
      short8 a0 = *(const short8*)(a2p + kt * 16);
      short8 a1 = *(const short8*)(a2p + 32 * 264 + kt * 16);
      a.a0 = MFMA(a0, fG3a[kt], a.a0);
      a.a1 = MFMA(a1, fG3a[kt], a.a1);
    }
    g3_epi(lds, a, ctg0, 0, wnet);
  }
  if (w == 0) {   // straggler unit: h-net tile 8 (cold loads)
    const unsigned short* bx = pw + OFF3H + (8 * 16 * 64 + l) * 8;
    int c = 8 * 32 + (l & 31);
    Acc2 a = acc_init((c < 528) ? hb3[c] : 0.f);
    #pragma unroll
    for (int kt = 0; kt < 16; kt++) {
      short8 a0 = *(const short8*)(a2hp + kt * 16);
      short8 a1 = *(const short8*)(a2hp + 32 * 264 + kt * 16);
      short8 b = *(const short8*)(bx + kt * 512);
      a.a0 = MFMA(a0, b, a.a0);
      a.a1 = MFMA(a1, b, a.a1);
    }
    g3_epi(lds, a, 8, 0, false);
  }
  // issue fG3b now (fG3a dead): latency hides under the spline's VALU work
  short8 fG3b[16];
  #pragma unroll
  for (int kt = 0; kt < 16; kt++) fG3b[kt] = *(const short8*)(bG3b + kt * 512);
  LGKM_BARRIER();

  spline_phase(lds, t, 0, xs0, y, r0);
  LGKM_BARRIER();

  // ---- G3 half 1: consume fG3b ----
  {
    float binit;
    if (wnet) binit = wb3[ctg1 * 32 + (l & 31)];
    else { int c = ctg1 * 32 + (l & 31); binit = (c < 528) ? hb3[c] : 0.f; }
    Acc2 a = acc_init(binit);
    #pragma unroll
    for (int kt = 0; kt < 16; kt++) {
      short8 a0 = *(const short8*)(a2p + kt * 16);
      short8 a1 = *(const short8*)(a2p + 32 * 264 + kt * 16);
      a.a0 = MFMA(a0, fG3b[kt], a.a0);
      a.a1 = MFMA(a1, fG3b[kt], a.a1);
    }
    g3_epi(lds, a, ctg1, 1, wnet);
  }
  if (w == 0) {   // straggler unit: h-net tile 16 (cold loads)
    const unsigned short* bx = pw + OFF3H + (16 * 16 * 64 + l) * 8;
    int c = 16 * 32 + (l & 31);
    Acc2 a = acc_init((c < 528) ? hb3[c] : 0.f);
    #pragma unroll
    for (int kt = 0; kt < 16; kt++) {
      short8 a0 = *(const short8*)(a2hp + kt * 16);
      short8 a1 = *(const short8*)(a2hp + 32 * 264 + kt * 16);
      short8 b = *(const short8*)(bx + kt * 512);
      a.a0 = MFMA(a0, b, a.a0);
      a.a1 = MFMA(a1, b, a.a1);
    }
    g3_epi(lds, a, 16, 1, false);
  }
  LGKM_BARRIER();

  spline_phase(lds, t, 1, xs1, y, r0);
}

extern "C" void kernel_launch(void* const* d_in, const int* in_sizes, int n_in,
                              void* d_out, int out_size, void* d_ws, size_t ws_size,
                              hipStream_t stream) {
  const float* x   = (const float*)d_in[0];
  const float* hW1 = (const float*)d_in[1];
  const float* hb1 = (const float*)d_in[2];
  const float* hW2 = (const float*)d_in[3];
  const float* hb2 = (const float*)d_in[4];
  const float* hW3 = (const float*)d_in[5];
  const float* hb3 = (const float*)d_in[6];
  const float* wW1 = (const float*)d_in[7];
  const float* wb1 = (const float*)d_in[8];
  const float* wW2 = (const float*)d_in[9];
  const float* wb2 = (const float*)d_in[10];
  const float* wW3 = (const float*)d_in[11];
  const float* wb3 = (const float*)d_in[12];
  unsigned short* pw = (unsigned short*)d_ws;

  pack_weights<<<800, 64, 0, stream>>>(hW1, wW1, hW2, wW2, hW3, wW3, pw);

  hipFuncSetAttribute((const void*)fused_kernel,
                      hipFuncAttributeMaxDynamicSharedMemorySize, LDS_TOTAL);
  fused_kernel<<<2048, 1024, LDS_TOTAL, stream>>>(
      x, hb1, hb2, hb3, wb1, wb2, wb3, pw, (float*)d_out);
}